// Round 2
// baseline (503.204 us; speedup 1.0000x reference)
//
#include <hip/hip_runtime.h>

// x: [B=16, C=64, H=256, W=256] fp32
// out = sigmoid(conv3x3(concat([max_c x, mean_c x]), w, SAME)) * x
//
// v3 = v2 with the register pin FIXED.
//  - v2's asm pin on f32x4 operands did NOT hold the payload (VGPR_Count 52 < 64
//    payload floats) -> compiler re-loaded x after the barrier = dependent L2
//    reload chain, 2.4 TB/s. v0's proven pin is per-SCALAR "+v" on a float
//    array; restored here.
//  - thread = 4 consecutive pixels x 16 channels -> 16x global_load_dwordx4
//    in, 16x nontemporal global_store_dwordx4 out; pooled partials combined
//    across the 4 channel-group lanes via shfl_xor(8|16) (in-wave: lane =
//    qx(3b) | g(2b) | qy&1 in bit5).
//  - XCD-chunked wgid swizzle (proven in v2: FETCH 392->237 MB, below the
//    256 MiB ideal -- halo re-reads hit same-XCD L2, L3 retains x across
//    dispatches).
//  - halo: 2 threads x 32 channels per ring pixel, pair-combined shfl_xor(1).
//  - nontemporal stores: write-once data must not evict x tiles from L2.

typedef float f32x4 __attribute__((ext_vector_type(4)));

#define TW 32
#define TH 8

__global__ __launch_bounds__(256) void spatial_attn_fused(
    const float* __restrict__ x,
    const float* __restrict__ wgt,
    float* __restrict__ out)
{
    constexpr int C = 64, H = 256, W = 256;
    constexpr int CG = 16;   // channels per thread

    // ---- XCD-chunked swizzle (round-robin wgid%8 -> XCD assumed) ----
    // grid = 4096 blocks = 8 XCDs x 512; each XCD owns 2 whole batches,
    // walking wtile fastest -> spatial neighbors share an XCD L2.
    const int lin = blockIdx.x + (int)gridDim.x * (blockIdx.y + (int)gridDim.y * blockIdx.z);
    const int xcd = lin & 7;
    const int nid = xcd * 512 + (lin >> 3);   // bijective: 4096 % 8 == 0
    const int b   = nid >> 8;                 // 256 tiles / batch
    const int rem = nid & 255;
    const int th  = (rem >> 3) * TH;          // htile 0..31
    const int tw  = (rem & 7) * TW;           // wtile 0..7 (fastest)

    const int tid = threadIdx.x;
    const int qx  = tid & 7;          // pixel-quad column 0..7 (pixels qx*4..qx*4+3)
    const int g   = (tid >> 3) & 3;   // channel group 0..3 (16 ch each)
    const int qy  = tid >> 5;         // row in tile 0..7

    const int h = th + qy;
    const int w = tw + qx * 4;

    __shared__ float smax[TH + 2][TW + 3];   // stride 35
    __shared__ float savg[TH + 2][TW + 3];

    const size_t cstride = (size_t)H * W;                              // 65536
    const size_t base    = ((size_t)(b * C + g * CG) * H + h) * W + w;

    // ---- interior: 16 channels x 4 pixels -> registers, pool in-register ----
    float xs[CG * 4];
    float mx[4] = { -INFINITY, -INFINITY, -INFINITY, -INFINITY };
    float sm[4] = { 0.0f, 0.0f, 0.0f, 0.0f };
#pragma unroll
    for (int i = 0; i < CG; ++i) {
        f32x4 v = *reinterpret_cast<const f32x4*>(x + base + (size_t)i * cstride);
#pragma unroll
        for (int j = 0; j < 4; ++j) {
            xs[i * 4 + j] = v[j];
            mx[j] = fmaxf(mx[j], v[j]);
            sm[j] += v[j];
        }
    }
    // Pin the payload in VGPRs, per scalar (v0-proven formula). Forbids the
    // compiler from dropping the loads and re-issuing them after the barrier.
#pragma unroll
    for (int i = 0; i < CG * 4; ++i) asm volatile("" : "+v"(xs[i]));

    // combine the 4 channel groups (lane bits 3..4) -> full 64-ch pool per pixel
#pragma unroll
    for (int j = 0; j < 4; ++j) {
        mx[j] = fmaxf(mx[j], __shfl_xor(mx[j], 8));
        sm[j] += __shfl_xor(sm[j], 8);
        mx[j] = fmaxf(mx[j], __shfl_xor(mx[j], 16));
        sm[j] += __shfl_xor(sm[j], 16);
    }

    if (g == 0) {
#pragma unroll
        for (int j = 0; j < 4; ++j) {
            smax[qy + 1][qx * 4 + 1 + j] = mx[j];
            savg[qy + 1][qx * 4 + 1 + j] = sm[j] * (1.0f / 64.0f);
        }
    }

    // ---- halo ring: 84 pixels, 2 threads x 32 channels each ----
    if (tid < 168) {
        const int hp   = tid >> 1;   // halo pixel 0..83
        const int half = tid & 1;    // channel half
        int hy, hx;
        if (hp < 34)      { hy = 0;              hx = hp;        }
        else if (hp < 68) { hy = TH + 1;         hx = hp - 34;   }
        else if (hp < 76) { hy = 1 + (hp - 68);  hx = 0;         }
        else              { hy = 1 + (hp - 76);  hx = TW + 1;    }
        const int gh = th + hy - 1;
        const int gw = tw + hx - 1;
        float m2 = 0.0f, s2 = 0.0f;             // zero-padding outside the image
        if (gh >= 0 && gh < H && gw >= 0 && gw < W) {
            const size_t hidx = ((size_t)(b * C + half * 32) * H + gh) * W + gw;
            m2 = -INFINITY;
#pragma unroll 8
            for (int c = 0; c < 32; ++c) {
                float v = x[hidx + (size_t)c * cstride];
                m2 = fmaxf(m2, v);
                s2 += v;
            }
        }
        m2 = fmaxf(m2, __shfl_xor(m2, 1));
        s2 += __shfl_xor(s2, 1);
        if (half == 0) {
            smax[hy][hx] = m2;
            savg[hy][hx] = s2 * (1.0f / 64.0f);
        }
    }
    __syncthreads();

    // ---- 3x3 conv (cross-correlation) + sigmoid, per thread's 4 pixels ----
    float att[4];
#pragma unroll
    for (int j = 0; j < 4; ++j) {
        const int px = qx * 4 + j;
        float acc = 0.0f;
#pragma unroll
        for (int kh = 0; kh < 3; ++kh) {
#pragma unroll
            for (int kw = 0; kw < 3; ++kw) {
                acc += wgt[kh * 3 + kw]     * smax[qy + kh][px + kw];
                acc += wgt[9 + kh * 3 + kw] * savg[qy + kh][px + kw];
            }
        }
        att[j] = 1.0f / (1.0f + __expf(-acc));
    }

    // ---- broadcast multiply from the pinned registers, nontemporal store ----
#pragma unroll
    for (int i = 0; i < CG; ++i) {
        f32x4 o;
#pragma unroll
        for (int j = 0; j < 4; ++j) o[j] = xs[i * 4 + j] * att[j];
        __builtin_nontemporal_store(o, reinterpret_cast<f32x4*>(out + base + (size_t)i * cstride));
    }
}

extern "C" void kernel_launch(void* const* d_in, const int* in_sizes, int n_in,
                              void* d_out, int out_size, void* d_ws, size_t ws_size,
                              hipStream_t stream) {
    const float* x   = (const float*)d_in[0];
    const float* wgt = (const float*)d_in[1];
    float* out = (float*)d_out;

    dim3 grid(256 / TW, 256 / TH, 16);   // (wtiles=8, htiles=32, batch=16)
    dim3 block(256);
    spatial_attn_fused<<<grid, block, 0, stream>>>(x, wgt, out);
}

// Round 3
// 502.489 us; speedup vs baseline: 1.0014x; 1.0014x over previous
//
#include <hip/hip_runtime.h>

// x: [B=16, C=64, H=256, W=256] fp32
// out = sigmoid(conv3x3(concat([max_c x, mean_c x]), w, SAME)) * x
//
// v4: interior x loads are explicit `asm volatile global_load_dwordx4`.
//  - v2/v3 post-mortem: empty-asm "+v" pins did NOT hold the payload
//    (VGPR_Count stayed 52 < 64 payload floats both rounds; dur identical).
//    The compiler re-reads x after the barrier -> dependent L2/L3 reload
//    chain -> 2.45 TB/s, 31% of peak, even though FETCH is already at the
//    single-read ideal. Volatile-asm loads cannot be rematerialized or
//    sunk: the 64 payload VGPRs MUST stay live across the barrier.
//  - drain with one `s_waitcnt vmcnt(0)` + sched_barrier(0) (rule 18:
//    hipcc hoists register-only consumers past inline-asm waits; the
//    sched_barrier is the fence).
//  - kept from v2/v3 (proven): XCD-chunked swizzle (FETCH 392->240 MB,
//    below ideal -- halo re-reads hit same-XCD L2, L3 retains x),
//    2-thread/32-ch halo split, dwordx4 nontemporal stores.

typedef float f32x4 __attribute__((ext_vector_type(4)));

#define TW 32
#define TH 8

__global__ __launch_bounds__(256) void spatial_attn_fused(
    const float* __restrict__ x,
    const float* __restrict__ wgt,
    float* __restrict__ out)
{
    constexpr int C = 64, H = 256, W = 256;
    constexpr int CG = 16;   // channels per thread

    // ---- XCD-chunked swizzle (round-robin wgid%8 -> XCD) ----
    // 4096 blocks = 8 XCDs x 512; each XCD owns 2 whole batches, wtile
    // fastest -> spatial neighbors share an XCD L2.
    const int lin = blockIdx.x + (int)gridDim.x * (blockIdx.y + (int)gridDim.y * blockIdx.z);
    const int xcd = lin & 7;
    const int nid = xcd * 512 + (lin >> 3);   // bijective: 4096 % 8 == 0
    const int b   = nid >> 8;                 // 256 tiles / batch
    const int rem = nid & 255;
    const int th  = (rem >> 3) * TH;          // htile 0..31
    const int tw  = (rem & 7) * TW;           // wtile 0..7 (fastest)

    const int tid = threadIdx.x;
    const int qx  = tid & 7;          // pixel-quad column 0..7 (pixels qx*4..qx*4+3)
    const int g   = (tid >> 3) & 3;   // channel group 0..3 (16 ch each)
    const int qy  = tid >> 5;         // row in tile 0..7

    const int h = th + qy;
    const int w = tw + qx * 4;

    __shared__ float smax[TH + 2][TW + 3];   // stride 35
    __shared__ float savg[TH + 2][TW + 3];

    const size_t cstride = (size_t)H * W;                              // 65536
    const size_t base    = ((size_t)(b * C + g * CG) * H + h) * W + w;

    // ---- interior: 16ch x 4px via volatile-asm dwordx4 (un-remat-able) ----
    f32x4 xv[CG];
    {
        const float* p = x + base;
#pragma unroll
        for (int i = 0; i < CG; ++i) {
            asm volatile("global_load_dwordx4 %0, %1, off"
                         : "=v"(xv[i])
                         : "v"(p + (size_t)i * cstride));
        }
        asm volatile("s_waitcnt vmcnt(0)" ::: "memory");
        __builtin_amdgcn_sched_barrier(0);   // rule 18: block consumer hoisting
    }

    float mx[4] = { -INFINITY, -INFINITY, -INFINITY, -INFINITY };
    float sm[4] = { 0.0f, 0.0f, 0.0f, 0.0f };
#pragma unroll
    for (int i = 0; i < CG; ++i) {
#pragma unroll
        for (int j = 0; j < 4; ++j) {
            mx[j] = fmaxf(mx[j], xv[i][j]);
            sm[j] += xv[i][j];
        }
    }

    // combine the 4 channel groups (lane bits 3..4) -> full 64-ch pool per pixel
#pragma unroll
    for (int j = 0; j < 4; ++j) {
        mx[j] = fmaxf(mx[j], __shfl_xor(mx[j], 8));
        sm[j] += __shfl_xor(sm[j], 8);
        mx[j] = fmaxf(mx[j], __shfl_xor(mx[j], 16));
        sm[j] += __shfl_xor(sm[j], 16);
    }

    if (g == 0) {
#pragma unroll
        for (int j = 0; j < 4; ++j) {
            smax[qy + 1][qx * 4 + 1 + j] = mx[j];
            savg[qy + 1][qx * 4 + 1 + j] = sm[j] * (1.0f / 64.0f);
        }
    }

    // ---- halo ring: 84 pixels, 2 threads x 32 channels each ----
    if (tid < 168) {
        const int hp   = tid >> 1;   // halo pixel 0..83
        const int half = tid & 1;    // channel half
        int hy, hx;
        if (hp < 34)      { hy = 0;              hx = hp;        }
        else if (hp < 68) { hy = TH + 1;         hx = hp - 34;   }
        else if (hp < 76) { hy = 1 + (hp - 68);  hx = 0;         }
        else              { hy = 1 + (hp - 76);  hx = TW + 1;    }
        const int gh = th + hy - 1;
        const int gw = tw + hx - 1;
        float m2 = 0.0f, s2 = 0.0f;             // zero-padding outside the image
        if (gh >= 0 && gh < H && gw >= 0 && gw < W) {
            const size_t hidx = ((size_t)(b * C + half * 32) * H + gh) * W + gw;
            m2 = -INFINITY;
#pragma unroll 8
            for (int c = 0; c < 32; ++c) {
                float v = x[hidx + (size_t)c * cstride];
                m2 = fmaxf(m2, v);
                s2 += v;
            }
        }
        m2 = fmaxf(m2, __shfl_xor(m2, 1));
        s2 += __shfl_xor(s2, 1);
        if (half == 0) {
            smax[hy][hx] = m2;
            savg[hy][hx] = s2 * (1.0f / 64.0f);
        }
    }
    __syncthreads();

    // ---- 3x3 conv (cross-correlation) + sigmoid, per thread's 4 pixels ----
    float att[4];
#pragma unroll
    for (int j = 0; j < 4; ++j) {
        const int px = qx * 4 + j;
        float acc = 0.0f;
#pragma unroll
        for (int kh = 0; kh < 3; ++kh) {
#pragma unroll
            for (int kw = 0; kw < 3; ++kw) {
                acc += wgt[kh * 3 + kw]     * smax[qy + kh][px + kw];
                acc += wgt[9 + kh * 3 + kw] * savg[qy + kh][px + kw];
            }
        }
        att[j] = 1.0f / (1.0f + __expf(-acc));
    }

    // ---- broadcast multiply from the asm-held registers, nontemporal store ----
#pragma unroll
    for (int i = 0; i < CG; ++i) {
        f32x4 o;
#pragma unroll
        for (int j = 0; j < 4; ++j) o[j] = xv[i][j] * att[j];
        __builtin_nontemporal_store(o, reinterpret_cast<f32x4*>(out + base + (size_t)i * cstride));
    }
}

extern "C" void kernel_launch(void* const* d_in, const int* in_sizes, int n_in,
                              void* d_out, int out_size, void* d_ws, size_t ws_size,
                              hipStream_t stream) {
    const float* x   = (const float*)d_in[0];
    const float* wgt = (const float*)d_in[1];
    float* out = (float*)d_out;

    dim3 grid(256 / TW, 256 / TH, 16);   // (wtiles=8, htiles=32, batch=16)
    dim3 block(256);
    spatial_attn_fused<<<grid, block, 0, stream>>>(x, wgt, out);
}

// Round 4
// 453.051 us; speedup vs baseline: 1.1107x; 1.1091x over previous
//
#include <hip/hip_runtime.h>

// x: [B=16, C=64, H=256, W=256] fp32
// out = sigmoid(conv3x3(concat([max_c x, mean_c x]), w, SAME)) * x
//
// v5: restore round-0's coherent DRAM front; keep vectorization + L2 halo
// locality.
//  - v2/v3/v4 post-mortem: payload-reload was FREE (v2 re-read x, v4 held it
//    in regs -- identical 209 us). The regression vs round 0 (188 us,
//    3.56 TB/s) was the ACCESS PATTERN: (a) nontemporal stores, (b) the
//    cross-batch XCD swizzle giving DRAM 8 scattered read + 8 scattered
//    write fronts instead of one coherent chip-wide front.
//  - v5 reverts nt -> plain stores, and uses a BANDED same-batch swizzle:
//    all XCDs walk the same batch together (coherent front), each XCD owns
//    a contiguous 4-tile-row band (halo neighbors same-XCD L2 -> keeps most
//    of the FETCH 392->245 MB win).
//  - kept: 16x asm-volatile global_load_dwordx4 (payload pinned, single
//    read), shfl-combined pooling, 2-thread/32-ch halo, dwordx4 stores.

typedef float f32x4 __attribute__((ext_vector_type(4)));

#define TW 32
#define TH 8

__global__ __launch_bounds__(256) void spatial_attn_fused(
    const float* __restrict__ x,
    const float* __restrict__ wgt,
    float* __restrict__ out)
{
    constexpr int C = 64, H = 256, W = 256;
    constexpr int CG = 16;   // channels per thread

    // ---- banded same-batch XCD swizzle (round-robin wgid%8 -> XCD) ----
    // lin = b*256 + inb*8 + xcd  (bijective over 4096)
    //   b   = lin >> 8          : all XCDs process batch b TOGETHER
    //   r   = xcd*4 + (inb>>3)  : each XCD owns a 4-tile-row band
    //   c   = inb & 7           : tw fastest within the band
    const int lin = blockIdx.x + (int)gridDim.x * (blockIdx.y + (int)gridDim.y * blockIdx.z);
    const int xcd = lin & 7;
    const int b   = lin >> 8;
    const int inb = (lin >> 3) & 31;
    const int th  = (xcd * 4 + (inb >> 3)) * TH;   // tile row 0..31
    const int tw  = (inb & 7) * TW;                // tile col 0..7

    const int tid = threadIdx.x;
    const int qx  = tid & 7;          // pixel-quad column 0..7 (pixels qx*4..qx*4+3)
    const int g   = (tid >> 3) & 3;   // channel group 0..3 (16 ch each)
    const int qy  = tid >> 5;         // row in tile 0..7

    const int h = th + qy;
    const int w = tw + qx * 4;

    __shared__ float smax[TH + 2][TW + 3];   // stride 35
    __shared__ float savg[TH + 2][TW + 3];

    const size_t cstride = (size_t)H * W;                              // 65536
    const size_t base    = ((size_t)(b * C + g * CG) * H + h) * W + w;

    // ---- interior: 16ch x 4px via volatile-asm dwordx4 (un-remat-able) ----
    f32x4 xv[CG];
    {
        const float* p = x + base;
#pragma unroll
        for (int i = 0; i < CG; ++i) {
            asm volatile("global_load_dwordx4 %0, %1, off"
                         : "=v"(xv[i])
                         : "v"(p + (size_t)i * cstride));
        }
        asm volatile("s_waitcnt vmcnt(0)" ::: "memory");
        __builtin_amdgcn_sched_barrier(0);   // rule 18: block consumer hoisting
    }

    float mx[4] = { -INFINITY, -INFINITY, -INFINITY, -INFINITY };
    float sm[4] = { 0.0f, 0.0f, 0.0f, 0.0f };
#pragma unroll
    for (int i = 0; i < CG; ++i) {
#pragma unroll
        for (int j = 0; j < 4; ++j) {
            mx[j] = fmaxf(mx[j], xv[i][j]);
            sm[j] += xv[i][j];
        }
    }

    // combine the 4 channel groups (lane bits 3..4) -> full 64-ch pool per pixel
#pragma unroll
    for (int j = 0; j < 4; ++j) {
        mx[j] = fmaxf(mx[j], __shfl_xor(mx[j], 8));
        sm[j] += __shfl_xor(sm[j], 8);
        mx[j] = fmaxf(mx[j], __shfl_xor(mx[j], 16));
        sm[j] += __shfl_xor(sm[j], 16);
    }

    if (g == 0) {
#pragma unroll
        for (int j = 0; j < 4; ++j) {
            smax[qy + 1][qx * 4 + 1 + j] = mx[j];
            savg[qy + 1][qx * 4 + 1 + j] = sm[j] * (1.0f / 64.0f);
        }
    }

    // ---- halo ring: 84 pixels, 2 threads x 32 channels each ----
    if (tid < 168) {
        const int hp   = tid >> 1;   // halo pixel 0..83
        const int half = tid & 1;    // channel half
        int hy, hx;
        if (hp < 34)      { hy = 0;              hx = hp;        }
        else if (hp < 68) { hy = TH + 1;         hx = hp - 34;   }
        else if (hp < 76) { hy = 1 + (hp - 68);  hx = 0;         }
        else              { hy = 1 + (hp - 76);  hx = TW + 1;    }
        const int gh = th + hy - 1;
        const int gw = tw + hx - 1;
        float m2 = 0.0f, s2 = 0.0f;             // zero-padding outside the image
        if (gh >= 0 && gh < H && gw >= 0 && gw < W) {
            const size_t hidx = ((size_t)(b * C + half * 32) * H + gh) * W + gw;
            m2 = -INFINITY;
#pragma unroll 8
            for (int c = 0; c < 32; ++c) {
                float v = x[hidx + (size_t)c * cstride];
                m2 = fmaxf(m2, v);
                s2 += v;
            }
        }
        m2 = fmaxf(m2, __shfl_xor(m2, 1));
        s2 += __shfl_xor(s2, 1);
        if (half == 0) {
            smax[hy][hx] = m2;
            savg[hy][hx] = s2 * (1.0f / 64.0f);
        }
    }
    __syncthreads();

    // ---- 3x3 conv (cross-correlation) + sigmoid, per thread's 4 pixels ----
    float att[4];
#pragma unroll
    for (int j = 0; j < 4; ++j) {
        const int px = qx * 4 + j;
        float acc = 0.0f;
#pragma unroll
        for (int kh = 0; kh < 3; ++kh) {
#pragma unroll
            for (int kw = 0; kw < 3; ++kw) {
                acc += wgt[kh * 3 + kw]     * smax[qy + kh][px + kw];
                acc += wgt[9 + kh * 3 + kw] * savg[qy + kh][px + kw];
            }
        }
        att[j] = 1.0f / (1.0f + __expf(-acc));
    }

    // ---- broadcast multiply from the asm-held registers, plain store ----
#pragma unroll
    for (int i = 0; i < CG; ++i) {
        f32x4 o;
#pragma unroll
        for (int j = 0; j < 4; ++j) o[j] = xv[i][j] * att[j];
        *reinterpret_cast<f32x4*>(out + base + (size_t)i * cstride) = o;
    }
}

extern "C" void kernel_launch(void* const* d_in, const int* in_sizes, int n_in,
                              void* d_out, int out_size, void* d_ws, size_t ws_size,
                              hipStream_t stream) {
    const float* x   = (const float*)d_in[0];
    const float* wgt = (const float*)d_in[1];
    float* out = (float*)d_out;

    dim3 grid(256 / TW, 256 / TH, 16);   // (wtiles=8, htiles=32, batch=16)
    dim3 block(256);
    spatial_attn_fused<<<grid, block, 0, stream>>>(x, wgt, out);
}